// Round 14
// baseline (142.649 us; speedup 1.0000x reference)
//
#include <hip/hip_runtime.h>
#include <hip/hip_bf16.h>

#define TB 128           // gather block (2 waves: cheap barriers, small tail)
#define TBB 1024         // block size for edge count/scatter (TLP for LDS-atomic chains)
#define BSH 8            // 256 nodes per bucket
#define BSZ 256
#define CHUNK 8192       // edges per block in bucket count/scatter
#define EBP 512          // padded blocks-per-bucket stride (EB <= 512)
#define TLS 1024         // localsort block size

// Load element i of p as float, where p is either f32 (isf32=1) or bf16 bits (isf32=0).
__device__ __forceinline__ float ldany(const void* __restrict__ p, size_t i, int isf32) {
  if (isf32) return ((const float*)p)[i];
  unsigned int u = ((const unsigned short*)p)[i];
  return __uint_as_float(u << 16);
}

// Pack two f32 into two bf16 (round-to-nearest-even): [lo | hi<<16].
__device__ __forceinline__ unsigned f2bf2(float lo, float hi) {
  unsigned ul = __float_as_uint(lo), uh = __float_as_uint(hi);
  ul += 0x7FFFu + ((ul >> 16) & 1u);
  uh += 0x7FFFu + ((uh >> 16) & 1u);
  return (ul >> 16) | (uh & 0xFFFF0000u);
}
__device__ __forceinline__ unsigned short f2bf1(float x) {
  unsigned u = __float_as_uint(x);
  u += 0x7FFFu + ((u >> 16) & 1u);
  return (unsigned short)(u >> 16);
}
__device__ __forceinline__ float bf_lo(unsigned u) { return __uint_as_float(u << 16); }
__device__ __forceinline__ float bf_hi(unsigned u) { return __uint_as_float(u & 0xFFFF0000u); }

// Inline dtype detect: bf16 N(0,1) exponent <= ~130; f32 misread as bf16 -> max >> 160.
// Call with the FULL block active; wave-uniform result.
__device__ __forceinline__ int detect_isf(const unsigned short* __restrict__ xb) {
  int lane = threadIdx.x & 63;
  int mx = 0;
  #pragma unroll
  for (int j = 0; j < 4; ++j) { int e = (xb[lane * 4 + j] >> 7) & 0xFF; mx = max(mx, e); }
  #pragma unroll
  for (int off = 32; off > 0; off >>= 1) mx = max(mx, __shfl_xor(mx, off));
  return mx > 160;
}

// ---------------- fused pass 1: edge histogram (blocks < EB) | proj1 (rest) ------
__global__ __launch_bounds__(TBB) void
k_bcount_proj(const int* __restrict__ ei, int E, int Et, int NB, int EB,
              int* __restrict__ bcnt,
              const unsigned short* __restrict__ xb,
              const void* __restrict__ Wg, const void* __restrict__ asg,
              const void* __restrict__ adg,
              unsigned* __restrict__ hb, unsigned* __restrict__ ab,
              float* __restrict__ ald, int n) {
  __shared__ int shmem[512];
  if (blockIdx.x < EB) {
    // ---- bucket histogram ----
    int* lcnt = shmem;
    for (int i = threadIdx.x; i < NB; i += TBB) lcnt[i] = 0;
    __syncthreads();
    long b0 = (long)blockIdx.x * CHUNK;
    int cnt = (int)(((long)Et - b0 < (long)CHUNK) ? ((long)Et - b0) : (long)CHUNK);
    for (int i = threadIdx.x * 4; i < cnt; i += TBB * 4) {
      long e = b0 + i;
      int rem = cnt - i;
      if (rem >= 4 && e + 3 < (long)E) {
        int4 d4 = *(const int4*)(ei + E + e);    // aligned: E%4==0, e%4==0
        atomicAdd(&lcnt[d4.x >> BSH], 1);
        atomicAdd(&lcnt[d4.y >> BSH], 1);
        atomicAdd(&lcnt[d4.z >> BSH], 1);
        atomicAdd(&lcnt[d4.w >> BSH], 1);
      } else {
        int m = rem < 4 ? rem : 4;
        for (int j = 0; j < m; ++j) {
          long ee = e + j;
          int d = (ee < E) ? ei[E + ee] : (int)(ee - E);
          atomicAdd(&lcnt[d >> BSH], 1);
        }
      }
    }
    __syncthreads();
    for (int i = threadIdx.x; i < NB; i += TBB)
      bcnt[(size_t)i * EBP + blockIdx.x] = lcnt[i];
  } else {
    // ---- layer-1 projection ----
    const int isf = detect_isf(xb);
    float* Ws = (float*)shmem;                   // 256 floats
    __shared__ float as_s[16], ad_s[16];
    for (int i = threadIdx.x; i < 256; i += TBB) Ws[i] = ldany(Wg, i, isf);
    if (threadIdx.x < 16) {
      as_s[threadIdx.x] = ldany(asg, threadIdx.x, isf);
      ad_s[threadIdx.x] = ldany(adg, threadIdx.x, isf);
    }
    __syncthreads();
    int nid = (blockIdx.x - EB) * TBB + threadIdx.x;
    if (nid >= n) return;

    float xr[16];
    #pragma unroll
    for (int i = 0; i < 16; ++i) xr[i] = ldany(xb, (size_t)nid * 16 + i, isf);

    float hv[16];
    #pragma unroll
    for (int j = 0; j < 16; ++j) hv[j] = 0.f;
    #pragma unroll
    for (int k = 0; k < 16; ++k) {
      #pragma unroll
      for (int j = 0; j < 16; ++j) hv[j] += xr[k] * Ws[k * 16 + j];
    }

    unsigned* row = hb + (size_t)nid * 8;
    ((uint4*)row)[0] = make_uint4(f2bf2(hv[0], hv[1]),  f2bf2(hv[2], hv[3]),
                                  f2bf2(hv[4], hv[5]),  f2bf2(hv[6], hv[7]));
    ((uint4*)row)[1] = make_uint4(f2bf2(hv[8], hv[9]),  f2bf2(hv[10], hv[11]),
                                  f2bf2(hv[12], hv[13]), f2bf2(hv[14], hv[15]));

    float s0 = 0.f, d0 = 0.f, s1 = 0.f, d1 = 0.f;
    #pragma unroll
    for (int c = 0; c < 8; ++c) {
      s0 += hv[c] * as_s[c];         d0 += hv[c] * ad_s[c];
      s1 += hv[8 + c] * as_s[8 + c]; d1 += hv[8 + c] * ad_s[8 + c];
    }
    ab[nid] = f2bf2(s0, s1);
    ((float2*)ald)[nid] = make_float2(d0, d1);
  }
}

// ---------------- pass 2: per-bucket exclusive scan over blocks -----------------
__global__ __launch_bounds__(EBP) void k_blockpfx(int* __restrict__ bcnt,
                                                  int* __restrict__ gcnt,
                                                  int EB, int NB) {
  __shared__ int sh[EBP];
  const int bk = blockIdx.x;
  const int tid = threadIdx.x;
  int v = (tid < EB) ? bcnt[(size_t)bk * EBP + tid] : 0;
  sh[tid] = v;
  __syncthreads();
  for (int off = 1; off < EBP; off <<= 1) {
    int t = (tid >= off) ? sh[tid - off] : 0;
    __syncthreads();
    sh[tid] += t;
    __syncthreads();
  }
  if (tid < EB) bcnt[(size_t)bk * EBP + tid] = sh[tid] - v;   // exclusive
  if (tid == 0) gcnt[bk] = sh[EBP - 1];                       // bucket total
}

// Exclusive scan over NB (<=1024) bucket totals; set gbase[NB]=Et.
__global__ void k_bscan(const int* __restrict__ gcnt, int* __restrict__ gbase,
                        int NB, int Et) {
  __shared__ int sh[1024];
  int tid = threadIdx.x;
  int v = (tid < NB) ? gcnt[tid] : 0;
  sh[tid] = v;
  __syncthreads();
  for (int off = 1; off < 1024; off <<= 1) {
    int t = (tid >= off) ? sh[tid - off] : 0;
    __syncthreads();
    sh[tid] += t;
    __syncthreads();
  }
  if (tid < NB) gbase[tid] = sh[tid] - v;
  if (tid == 0) gbase[NB] = Et;
}

// ---------------- pass 3: single-pass scatter using precomputed bases -----------
__global__ __launch_bounds__(TBB) void k_bscatter(const int* __restrict__ ei, int E, int Et,
                                                  int NB, const int* __restrict__ gbase,
                                                  const int* __restrict__ bcnt,
                                                  int* __restrict__ packed) {
  __shared__ int lcur[512];
  const int b = blockIdx.x;
  for (int i = threadIdx.x; i < NB; i += TBB)
    lcur[i] = gbase[i] + bcnt[(size_t)i * EBP + b];
  __syncthreads();
  long b0 = (long)b * CHUNK;
  int cnt = (int)(((long)Et - b0 < (long)CHUNK) ? ((long)Et - b0) : (long)CHUNK);
  for (int i = threadIdx.x * 4; i < cnt; i += TBB * 4) {
    long e = b0 + i;
    int rem = cnt - i;
    if (rem >= 4 && e + 3 < (long)E) {
      int4 s4 = *(const int4*)(ei + e);
      int4 d4 = *(const int4*)(ei + E + e);
      int bk, pos;
      bk = d4.x >> BSH; pos = atomicAdd(&lcur[bk], 1); packed[pos] = ((d4.x & (BSZ-1)) << 17) | s4.x;
      bk = d4.y >> BSH; pos = atomicAdd(&lcur[bk], 1); packed[pos] = ((d4.y & (BSZ-1)) << 17) | s4.y;
      bk = d4.z >> BSH; pos = atomicAdd(&lcur[bk], 1); packed[pos] = ((d4.z & (BSZ-1)) << 17) | s4.z;
      bk = d4.w >> BSH; pos = atomicAdd(&lcur[bk], 1); packed[pos] = ((d4.w & (BSZ-1)) << 17) | s4.w;
    } else {
      int m = rem < 4 ? rem : 4;
      for (int j = 0; j < m; ++j) {
        long ee = e + j;
        int s, d;
        if (ee < E) { s = ei[ee]; d = ei[E + ee]; }
        else        { s = (int)(ee - E); d = s; }
        int bk = d >> BSH;
        int pos = atomicAdd(&lcur[bk], 1);
        packed[pos] = ((d & (BSZ - 1)) << 17) | s;
      }
    }
  }
}

// Local counting sort within each bucket -> full dst-sorted CSR + rowptr.
__global__ __launch_bounds__(TLS) void k_localsort(const int* __restrict__ gbase,
                                                   const int* __restrict__ packed,
                                                   int* __restrict__ rowptr,
                                                   int* __restrict__ csr,
                                                   int n, int Et) {
  __shared__ int lcnt[BSZ], lbase[BSZ], sh[BSZ];
  const int b = blockIdx.x;
  const int node0 = b << BSH;
  const int tid = threadIdx.x;
  if (tid < BSZ) lcnt[tid] = 0;
  __syncthreads();
  const int beg = gbase[b], end = gbase[b + 1];
  for (int k = beg + tid; k < end; k += TLS)
    atomicAdd(&lcnt[packed[k] >> 17], 1);
  __syncthreads();
  int v = (tid < BSZ) ? lcnt[tid] : 0;
  if (tid < BSZ) sh[tid] = v;
  __syncthreads();
  for (int off = 1; off < BSZ; off <<= 1) {
    int t = (tid < BSZ && tid >= off) ? sh[tid - off] : 0;
    __syncthreads();
    if (tid < BSZ) sh[tid] += t;
    __syncthreads();
  }
  if (tid < BSZ) lbase[tid] = sh[tid] - v;
  __syncthreads();
  const int nn = min(BSZ, n - node0);
  if (tid < nn) rowptr[node0 + tid] = beg + lbase[tid];
  if (b == 0 && tid == 0) rowptr[n] = Et;
  for (int k = beg + tid; k < end; k += TLS) {
    int p = packed[k];
    int dl = p >> 17;
    int pos = beg + atomicAdd(&lbase[dl], 1);
    csr[pos] = p & 0x1FFFF;
  }
}

// ---------------- Layer-1 gather: 128-thr blocks, 16 lanes/node, 2-deep pipeline -
// Fused finalize + proj2 spread over 64 threads (thread = node x out-channel).
__global__ __launch_bounds__(TB) void
gat_gather1(const int* __restrict__ rowptr, const int* __restrict__ csr,
            const unsigned* __restrict__ hb, const unsigned* __restrict__ ab,
            const float* __restrict__ ald,
            const void* __restrict__ bias,
            const void* __restrict__ W2g, const void* __restrict__ as2g,
            const void* __restrict__ ad2g,
            unsigned* __restrict__ hb2, unsigned* __restrict__ ab2,
            float* __restrict__ ald2,
            int n, const unsigned short* __restrict__ xb) {
  const int isf = detect_isf(xb);
  __shared__ float sb[16];
  __shared__ float sv[8 * 17];     // 8 nodes/block, stride 17
  __shared__ float sh2[8 * 9];     // staged h2 rows for att2 dots
  __shared__ float W2s[128];
  __shared__ float as2s[8], ad2s[8];
  if (threadIdx.x < 16) sb[threadIdx.x] = ldany(bias, threadIdx.x, isf);
  if (threadIdx.x >= 16 && threadIdx.x < 24) {
    as2s[threadIdx.x - 16] = ldany(as2g, threadIdx.x - 16, isf);
    ad2s[threadIdx.x - 16] = ldany(ad2g, threadIdx.x - 16, isf);
  }
  if (threadIdx.x < 128) W2s[threadIdx.x] = ldany(W2g, threadIdx.x, isf);
  __syncthreads();

  const int t = blockIdx.x * TB + threadIdx.x;
  const int sub = t & 15, nid = t >> 4;
  const int slot = sub >> 1, hq = sub & 1;      // 8 edge slots x 2 head-lanes
  const bool act = nid < n;
  int beg = 0, end = 0;
  float aldv = 0.f;
  if (act) {
    beg = rowptr[nid];
    end = rowptr[nid + 1];
    aldv = ald[(size_t)nid * 2 + hq];
  }

  float acc[8];
  #pragma unroll
  for (int c = 0; c < 8; ++c) acc[c] = 0.f;
  float z = 0.f;

  // ---- 2-deep software pipeline: row/ab loads 1 iter ahead, csr 2 ahead ----
  int k  = beg + slot;
  int kn = k + 8;
  int s_cur = (k  < end) ? csr[k]  : 0;
  int s_nxt = (kn < end) ? csr[kn] : 0;
  uint4    u_cur = *(const uint4*)(hb + (size_t)s_cur * 8 + hq * 4);
  unsigned a_cur = ab[s_cur];
  while (k < end) {
    uint4    u_n = *(const uint4*)(hb + (size_t)s_nxt * 8 + hq * 4);  // next row
    unsigned a_n = ab[s_nxt];
    int kf = kn + 8;
    int s_f = (kf < end) ? csr[kf] : 0;          // csr two ahead
    float alsv = hq ? bf_hi(a_cur) : bf_lo(a_cur);
    float lg = alsv + aldv;
    lg = lg > 0.f ? lg : 0.2f * lg;              // leaky_relu slope 0.2
    float w = __expf(lg);
    z += w;
    acc[0] += w * bf_lo(u_cur.x); acc[1] += w * bf_hi(u_cur.x);
    acc[2] += w * bf_lo(u_cur.y); acc[3] += w * bf_hi(u_cur.y);
    acc[4] += w * bf_lo(u_cur.z); acc[5] += w * bf_hi(u_cur.z);
    acc[6] += w * bf_lo(u_cur.w); acc[7] += w * bf_hi(u_cur.w);
    k = kn; kn = kf; s_cur = s_nxt; s_nxt = s_f; u_cur = u_n; a_cur = a_n;
  }

  #pragma unroll
  for (int off = 2; off < 16; off <<= 1) {      // combine slots, keep head bit
    z += __shfl_xor(z, off);
    #pragma unroll
    for (int c = 0; c < 8; ++c) acc[c] += __shfl_xor(acc[c], off);
  }
  float inv = 1.f / (z + 1e-16f);

  if (act && slot == 0) {                       // lanes sub=0(head0),1(head1)
    int ns = threadIdx.x >> 4;
    #pragma unroll
    for (int c = 0; c < 8; ++c) {
      float v = acc[c] * inv + sb[hq * 8 + c];
      v = v > 0.f ? v : expm1f(v);              // ELU
      sv[ns * 17 + hq * 8 + c] = v;
    }
  }
  __syncthreads();
  // ---- proj2 spread: thread j<64 = (node ns, out channel) : 16 MACs ----
  {
    int j = threadIdx.x;
    if (j < 64) {
      int ns = j >> 3, out = j & 7;
      int nid2 = blockIdx.x * 8 + ns;
      if (nid2 < n) {
        float h2v = 0.f;
        #pragma unroll
        for (int kk = 0; kk < 16; ++kk) h2v += sv[ns * 17 + kk] * W2s[kk * 8 + out];
        ((unsigned short*)hb2)[(size_t)nid2 * 8 + out] = f2bf1(h2v);
        sh2[ns * 9 + out] = h2v;
      }
    }
  }
  __syncthreads();
  // ---- att2 dots: thread j<8 = node ----
  {
    int j = threadIdx.x;
    if (j < 8) {
      int nid2 = blockIdx.x * 8 + j;
      if (nid2 < n) {
        float s20 = 0.f, d20 = 0.f, s21 = 0.f, d21 = 0.f;
        #pragma unroll
        for (int c = 0; c < 4; ++c) {
          float h0 = sh2[j * 9 + c], h1 = sh2[j * 9 + 4 + c];
          s20 += h0 * as2s[c];     d20 += h0 * ad2s[c];
          s21 += h1 * as2s[4 + c]; d21 += h1 * ad2s[4 + c];
        }
        ab2[nid2] = f2bf2(s20, s21);
        ((float2*)ald2)[nid2] = make_float2(d20, d21);
      }
    }
  }
}

// ---------------- Layer-2 gather: 128-thr blocks, 2 lanes/edge (8B), pipelined ---
__global__ __launch_bounds__(TB) void
gat_gather2(const int* __restrict__ rowptr, const int* __restrict__ csr,
            const unsigned* __restrict__ hb2, const unsigned* __restrict__ ab2,
            const float* __restrict__ ald2,
            const void* __restrict__ bias,
            void* __restrict__ outp, int n, const unsigned short* __restrict__ xb) {
  const int isf = detect_isf(xb);
  __shared__ float sb[8];
  if (threadIdx.x < 8) sb[threadIdx.x] = ldany(bias, threadIdx.x, isf);
  __syncthreads();

  const int t = blockIdx.x * TB + threadIdx.x;
  const int sub = t & 15, nid = t >> 4;
  const int slot = sub >> 1, hq = sub & 1;      // 8 edge slots x 2 head-lanes
  const bool act = nid < n;
  int beg = 0, end = 0;
  float aldv = 0.f;
  if (act) {
    beg = rowptr[nid];
    end = rowptr[nid + 1];
    aldv = ald2[(size_t)nid * 2 + hq];
  }

  float a0 = 0.f, a1 = 0.f, a2 = 0.f, a3 = 0.f, z = 0.f;

  int k  = beg + slot;
  int kn = k + 8;
  int s_cur = (k  < end) ? csr[k]  : 0;
  int s_nxt = (kn < end) ? csr[kn] : 0;
  uint2    u_cur = *(const uint2*)(hb2 + (size_t)s_cur * 4 + hq * 2);
  unsigned ab_cur = ab2[s_cur];
  while (k < end) {
    uint2    u_n = *(const uint2*)(hb2 + (size_t)s_nxt * 4 + hq * 2);
    unsigned ab_n = ab2[s_nxt];
    int kf = kn + 8;
    int s_f = (kf < end) ? csr[kf] : 0;
    float alsv = hq ? bf_hi(ab_cur) : bf_lo(ab_cur);
    float lg = alsv + aldv;
    lg = lg > 0.f ? lg : 0.2f * lg;
    float w = __expf(lg);
    z += w;
    a0 += w * bf_lo(u_cur.x); a1 += w * bf_hi(u_cur.x);
    a2 += w * bf_lo(u_cur.y); a3 += w * bf_hi(u_cur.y);
    k = kn; kn = kf; s_cur = s_nxt; s_nxt = s_f; u_cur = u_n; ab_cur = ab_n;
  }

  #pragma unroll
  for (int off = 2; off < 16; off <<= 1) {      // combine slots, keep head bit
    z  += __shfl_xor(z, off);
    a0 += __shfl_xor(a0, off); a1 += __shfl_xor(a1, off);
    a2 += __shfl_xor(a2, off); a3 += __shfl_xor(a3, off);
  }

  if (act && slot == 0) {                       // lanes sub=0(head0),1(head1)
    float inv = 1.f / (z + 1e-16f);
    float v0 = a0 * inv + sb[hq * 4 + 0];
    float v1 = a1 * inv + sb[hq * 4 + 1];
    float v2 = a2 * inv + sb[hq * 4 + 2];
    float v3 = a3 * inv + sb[hq * 4 + 3];
    if (isf) {
      ((float4*)outp)[(size_t)nid * 2 + hq] = make_float4(v0, v1, v2, v3);
    } else {
      ((uint2*)outp)[(size_t)nid * 2 + hq] = make_uint2(f2bf2(v0, v1), f2bf2(v2, v3));
    }
  }
}

extern "C" void kernel_launch(void* const* d_in, const int* in_sizes, int n_in,
                              void* d_out, int out_size, void* d_ws, size_t ws_size,
                              hipStream_t stream) {
  const unsigned short* xb = (const unsigned short*)d_in[0];
  const int*  ei  = (const int*)d_in[1];
  const void* W1  = d_in[2];
  const void* as1 = d_in[3];
  const void* ad1 = d_in[4];
  const void* b1  = d_in[5];
  const void* W2  = d_in[6];
  const void* as2 = d_in[7];
  const void* ad2 = d_in[8];
  const void* b2  = d_in[9];

  const int n  = in_sizes[0] / 16;        // 100000
  const int E  = in_sizes[1] / 2;         // 3200000
  const int Et = E + n;                   // + self-loops
  const int NB = (n + BSZ - 1) >> BSH;    // 391 buckets
  const int EB = (Et + CHUNK - 1) / CHUNK;  // 403 edge-chunk blocks (<= EBP)

  // ---- workspace layout (no unions; ws is large) ----
  char* base = (char*)d_ws;
  int* gcnt   = (int*)(base + 64);        // NB+1
  int* gbase_ = gcnt + (NB + 1);          // NB+1
  int* rowptr = gbase_ + (NB + 1);        // n+1
  int* bcnt   = rowptr + (n + 1);         // NB * EBP
  int* csr    = bcnt + (size_t)NB * EBP;  // Et
  int* packed = csr + Et;                 // Et
  size_t off1 = 64 + sizeof(int) * ((size_t)(NB + 1) * 2 + (size_t)(n + 1)
                                    + (size_t)NB * EBP + 2 * (size_t)Et);
  off1 = (off1 + 255) & ~(size_t)255;
  unsigned* hb1  = (unsigned*)(base + off1);                  // 32n B
  float*    ald1 = (float*)(base + off1 + (size_t)32 * n);    // 8n B
  unsigned* ab1  = (unsigned*)(base + off1 + (size_t)40 * n); // 4n B
  size_t off2 = off1 + (size_t)44 * n;
  off2 = (off2 + 255) & ~(size_t)255;
  unsigned* hb2  = (unsigned*)(base + off2);                  // 16n B
  float*    ald2 = (float*)(base + off2 + (size_t)16 * n);    // 8n B
  unsigned* ab2  = (unsigned*)(base + off2 + (size_t)24 * n); // 4n B

  const int pblk = (n + TBB - 1) / TBB;           // proj blocks
  const int gblk = (16 * n + TB - 1) / TB;        // 16 threads per node

  // ---- fused: edge histogram + layer-1 proj (independent work, one dispatch) ----
  k_bcount_proj<<<EB + pblk, TBB, 0, stream>>>(ei, E, Et, NB, EB, bcnt,
                                               xb, W1, as1, ad1, hb1, ab1, ald1, n);
  k_blockpfx<<<NB, EBP, 0, stream>>>(bcnt, gcnt, EB, NB);
  k_bscan<<<1, 1024, 0, stream>>>(gcnt, gbase_, NB, Et);
  k_bscatter<<<EB, TBB, 0, stream>>>(ei, E, Et, NB, gbase_, bcnt, packed);
  k_localsort<<<NB, TLS, 0, stream>>>(gbase_, packed, rowptr, csr, n, Et);

  // ---- Layer 1 gather + finalize + fused proj2 -> layer-2 tables ----
  gat_gather1<<<gblk, TB, 0, stream>>>(rowptr, csr, hb1, ab1, ald1, b1,
                                       W2, as2, ad2, hb2, ab2, ald2, n, xb);

  // ---- Layer 2 gather + finalize -> d_out ----
  gat_gather2<<<gblk, TB, 0, stream>>>(rowptr, csr, hb2, ab2, ald2, b2,
                                       d_out, n, xb);
}

// Round 15
// 123.467 us; speedup vs baseline: 1.1554x; 1.1554x over previous
//
#include <hip/hip_runtime.h>
#include <hip/hip_bf16.h>

#define TB 128           // gather block (2 waves)
#define TBB 1024         // block size for edge count/scatter
#define BSH 8            // 256 nodes per bucket
#define BSZ 256
#define CHUNK 8192       // edges per block in bucket count/scatter
#define EBP 512          // padded blocks-per-bucket stride (EB <= 512)
#define TLS 1024         // localsort block size

// Load element i of p as float, where p is either f32 (isf32=1) or bf16 bits (isf32=0).
__device__ __forceinline__ float ldany(const void* __restrict__ p, size_t i, int isf32) {
  if (isf32) return ((const float*)p)[i];
  unsigned int u = ((const unsigned short*)p)[i];
  return __uint_as_float(u << 16);
}

// Pack two f32 into two bf16 (round-to-nearest-even): [lo | hi<<16].
__device__ __forceinline__ unsigned f2bf2(float lo, float hi) {
  unsigned ul = __float_as_uint(lo), uh = __float_as_uint(hi);
  ul += 0x7FFFu + ((ul >> 16) & 1u);
  uh += 0x7FFFu + ((uh >> 16) & 1u);
  return (ul >> 16) | (uh & 0xFFFF0000u);
}
__device__ __forceinline__ unsigned short f2bf1(float x) {
  unsigned u = __float_as_uint(x);
  u += 0x7FFFu + ((u >> 16) & 1u);
  return (unsigned short)(u >> 16);
}
__device__ __forceinline__ float bf_lo(unsigned u) { return __uint_as_float(u << 16); }
__device__ __forceinline__ float bf_hi(unsigned u) { return __uint_as_float(u & 0xFFFF0000u); }

// Inline dtype detect: bf16 N(0,1) exponent <= ~130; f32 misread as bf16 -> max >> 160.
// Call with the FULL block active; wave-uniform result.
__device__ __forceinline__ int detect_isf(const unsigned short* __restrict__ xb) {
  int lane = threadIdx.x & 63;
  int mx = 0;
  #pragma unroll
  for (int j = 0; j < 4; ++j) { int e = (xb[lane * 4 + j] >> 7) & 0xFF; mx = max(mx, e); }
  #pragma unroll
  for (int off = 32; off > 0; off >>= 1) mx = max(mx, __shfl_xor(mx, off));
  return mx > 160;
}

// ---------------- fused pass 1: edge histogram (blocks < EB) | proj1 (rest) ------
__global__ __launch_bounds__(TBB) void
k_bcount_proj(const int* __restrict__ ei, int E, int Et, int NB, int EB,
              int* __restrict__ bcnt,
              const unsigned short* __restrict__ xb,
              const void* __restrict__ Wg, const void* __restrict__ adg,
              unsigned* __restrict__ hb, float* __restrict__ ald, int n) {
  __shared__ int shmem[512];
  if (blockIdx.x < EB) {
    // ---- bucket histogram ----
    int* lcnt = shmem;
    for (int i = threadIdx.x; i < NB; i += TBB) lcnt[i] = 0;
    __syncthreads();
    long b0 = (long)blockIdx.x * CHUNK;
    int cnt = (int)(((long)Et - b0 < (long)CHUNK) ? ((long)Et - b0) : (long)CHUNK);
    for (int i = threadIdx.x * 4; i < cnt; i += TBB * 4) {
      long e = b0 + i;
      int rem = cnt - i;
      if (rem >= 4 && e + 3 < (long)E) {
        int4 d4 = *(const int4*)(ei + E + e);    // aligned: E%4==0, e%4==0
        atomicAdd(&lcnt[d4.x >> BSH], 1);
        atomicAdd(&lcnt[d4.y >> BSH], 1);
        atomicAdd(&lcnt[d4.z >> BSH], 1);
        atomicAdd(&lcnt[d4.w >> BSH], 1);
      } else {
        int m = rem < 4 ? rem : 4;
        for (int j = 0; j < m; ++j) {
          long ee = e + j;
          int d = (ee < E) ? ei[E + ee] : (int)(ee - E);
          atomicAdd(&lcnt[d >> BSH], 1);
        }
      }
    }
    __syncthreads();
    for (int i = threadIdx.x; i < NB; i += TBB)
      bcnt[(size_t)i * EBP + blockIdx.x] = lcnt[i];
  } else {
    // ---- layer-1 projection: hb row (16 bf16) + ald (f32x2); als computed in gather ----
    const int isf = detect_isf(xb);
    float* Ws = (float*)shmem;                   // 256 floats
    __shared__ float ad_s[16];
    for (int i = threadIdx.x; i < 256; i += TBB) Ws[i] = ldany(Wg, i, isf);
    if (threadIdx.x < 16) ad_s[threadIdx.x] = ldany(adg, threadIdx.x, isf);
    __syncthreads();
    int nid = (blockIdx.x - EB) * TBB + threadIdx.x;
    if (nid >= n) return;

    float xr[16];
    #pragma unroll
    for (int i = 0; i < 16; ++i) xr[i] = ldany(xb, (size_t)nid * 16 + i, isf);

    float hv[16];
    #pragma unroll
    for (int j = 0; j < 16; ++j) hv[j] = 0.f;
    #pragma unroll
    for (int k = 0; k < 16; ++k) {
      #pragma unroll
      for (int j = 0; j < 16; ++j) hv[j] += xr[k] * Ws[k * 16 + j];
    }

    unsigned* row = hb + (size_t)nid * 8;
    ((uint4*)row)[0] = make_uint4(f2bf2(hv[0], hv[1]),  f2bf2(hv[2], hv[3]),
                                  f2bf2(hv[4], hv[5]),  f2bf2(hv[6], hv[7]));
    ((uint4*)row)[1] = make_uint4(f2bf2(hv[8], hv[9]),  f2bf2(hv[10], hv[11]),
                                  f2bf2(hv[12], hv[13]), f2bf2(hv[14], hv[15]));

    float d0 = 0.f, d1 = 0.f;
    #pragma unroll
    for (int c = 0; c < 8; ++c) {
      d0 += hv[c] * ad_s[c];
      d1 += hv[8 + c] * ad_s[8 + c];
    }
    ((float2*)ald)[nid] = make_float2(d0, d1);
  }
}

// ---------------- pass 2: per-bucket exclusive scan over blocks -----------------
__global__ __launch_bounds__(EBP) void k_blockpfx(int* __restrict__ bcnt,
                                                  int* __restrict__ gcnt,
                                                  int EB, int NB) {
  __shared__ int sh[EBP];
  const int bk = blockIdx.x;
  const int tid = threadIdx.x;
  int v = (tid < EB) ? bcnt[(size_t)bk * EBP + tid] : 0;
  sh[tid] = v;
  __syncthreads();
  for (int off = 1; off < EBP; off <<= 1) {
    int t = (tid >= off) ? sh[tid - off] : 0;
    __syncthreads();
    sh[tid] += t;
    __syncthreads();
  }
  if (tid < EB) bcnt[(size_t)bk * EBP + tid] = sh[tid] - v;   // exclusive
  if (tid == 0) gcnt[bk] = sh[EBP - 1];                       // bucket total
}

// Exclusive scan over NB (<=1024) bucket totals; set gbase[NB]=Et.
__global__ void k_bscan(const int* __restrict__ gcnt, int* __restrict__ gbase,
                        int NB, int Et) {
  __shared__ int sh[1024];
  int tid = threadIdx.x;
  int v = (tid < NB) ? gcnt[tid] : 0;
  sh[tid] = v;
  __syncthreads();
  for (int off = 1; off < 1024; off <<= 1) {
    int t = (tid >= off) ? sh[tid - off] : 0;
    __syncthreads();
    sh[tid] += t;
    __syncthreads();
  }
  if (tid < NB) gbase[tid] = sh[tid] - v;
  if (tid == 0) gbase[NB] = Et;
}

// ---------------- pass 3: single-pass scatter using precomputed bases -----------
__global__ __launch_bounds__(TBB) void k_bscatter(const int* __restrict__ ei, int E, int Et,
                                                  int NB, const int* __restrict__ gbase,
                                                  const int* __restrict__ bcnt,
                                                  int* __restrict__ packed) {
  __shared__ int lcur[512];
  const int b = blockIdx.x;
  for (int i = threadIdx.x; i < NB; i += TBB)
    lcur[i] = gbase[i] + bcnt[(size_t)i * EBP + b];
  __syncthreads();
  long b0 = (long)b * CHUNK;
  int cnt = (int)(((long)Et - b0 < (long)CHUNK) ? ((long)Et - b0) : (long)CHUNK);
  for (int i = threadIdx.x * 4; i < cnt; i += TBB * 4) {
    long e = b0 + i;
    int rem = cnt - i;
    if (rem >= 4 && e + 3 < (long)E) {
      int4 s4 = *(const int4*)(ei + e);
      int4 d4 = *(const int4*)(ei + E + e);
      int bk, pos;
      bk = d4.x >> BSH; pos = atomicAdd(&lcur[bk], 1); packed[pos] = ((d4.x & (BSZ-1)) << 17) | s4.x;
      bk = d4.y >> BSH; pos = atomicAdd(&lcur[bk], 1); packed[pos] = ((d4.y & (BSZ-1)) << 17) | s4.y;
      bk = d4.z >> BSH; pos = atomicAdd(&lcur[bk], 1); packed[pos] = ((d4.z & (BSZ-1)) << 17) | s4.z;
      bk = d4.w >> BSH; pos = atomicAdd(&lcur[bk], 1); packed[pos] = ((d4.w & (BSZ-1)) << 17) | s4.w;
    } else {
      int m = rem < 4 ? rem : 4;
      for (int j = 0; j < m; ++j) {
        long ee = e + j;
        int s, d;
        if (ee < E) { s = ei[ee]; d = ei[E + ee]; }
        else        { s = (int)(ee - E); d = s; }
        int bk = d >> BSH;
        int pos = atomicAdd(&lcur[bk], 1);
        packed[pos] = ((d & (BSZ - 1)) << 17) | s;
      }
    }
  }
}

// Local counting sort within each bucket -> full dst-sorted CSR + rowptr.
__global__ __launch_bounds__(TLS) void k_localsort(const int* __restrict__ gbase,
                                                   const int* __restrict__ packed,
                                                   int* __restrict__ rowptr,
                                                   int* __restrict__ csr,
                                                   int n, int Et) {
  __shared__ int lcnt[BSZ], lbase[BSZ], sh[BSZ];
  const int b = blockIdx.x;
  const int node0 = b << BSH;
  const int tid = threadIdx.x;
  if (tid < BSZ) lcnt[tid] = 0;
  __syncthreads();
  const int beg = gbase[b], end = gbase[b + 1];
  for (int k = beg + tid; k < end; k += TLS)
    atomicAdd(&lcnt[packed[k] >> 17], 1);
  __syncthreads();
  int v = (tid < BSZ) ? lcnt[tid] : 0;
  if (tid < BSZ) sh[tid] = v;
  __syncthreads();
  for (int off = 1; off < BSZ; off <<= 1) {
    int t = (tid < BSZ && tid >= off) ? sh[tid - off] : 0;
    __syncthreads();
    if (tid < BSZ) sh[tid] += t;
    __syncthreads();
  }
  if (tid < BSZ) lbase[tid] = sh[tid] - v;
  __syncthreads();
  const int nn = min(BSZ, n - node0);
  if (tid < nn) rowptr[node0 + tid] = beg + lbase[tid];
  if (b == 0 && tid == 0) rowptr[n] = Et;
  for (int k = beg + tid; k < end; k += TLS) {
    int p = packed[k];
    int dl = p >> 17;
    int pos = beg + atomicAdd(&lbase[dl], 1);
    csr[pos] = p & 0x1FFFF;
  }
}

// ---------------- Layer-1 gather: 1 scattered load/edge; als computed in-regs ----
__global__ __launch_bounds__(TB) void
gat_gather1(const int* __restrict__ rowptr, const int* __restrict__ csr,
            const unsigned* __restrict__ hb, const float* __restrict__ ald,
            const void* __restrict__ bias, const void* __restrict__ as1g,
            const void* __restrict__ W2g, const void* __restrict__ ad2g,
            unsigned* __restrict__ hb2, float* __restrict__ ald2,
            int n, const unsigned short* __restrict__ xb) {
  const int isf = detect_isf(xb);
  __shared__ float sb[16];
  __shared__ float as1s[16];
  __shared__ float sv[8 * 17];     // 8 nodes/block, stride 17
  __shared__ float sh2[8 * 9];     // staged h2 rows for ald2 dots
  __shared__ float W2s[128];
  __shared__ float ad2s[8];
  if (threadIdx.x < 16) sb[threadIdx.x] = ldany(bias, threadIdx.x, isf);
  if (threadIdx.x >= 16 && threadIdx.x < 32) as1s[threadIdx.x - 16] = ldany(as1g, threadIdx.x - 16, isf);
  if (threadIdx.x >= 32 && threadIdx.x < 40) ad2s[threadIdx.x - 32] = ldany(ad2g, threadIdx.x - 32, isf);
  if (threadIdx.x < 128) W2s[threadIdx.x] = ldany(W2g, threadIdx.x, isf);
  __syncthreads();

  const int t = blockIdx.x * TB + threadIdx.x;
  const int sub = t & 15, nid = t >> 4;
  const int slot = sub >> 1, hq = sub & 1;      // 8 edge slots x 2 head-lanes
  const bool act = nid < n;
  int beg = 0, end = 0;
  float aldv = 0.f;
  float as_r[8];
  #pragma unroll
  for (int c = 0; c < 8; ++c) as_r[c] = as1s[hq * 8 + c];
  if (act) {
    beg = rowptr[nid];
    end = rowptr[nid + 1];
    aldv = ald[(size_t)nid * 2 + hq];
  }

  float acc[8];
  #pragma unroll
  for (int c = 0; c < 8; ++c) acc[c] = 0.f;
  float z = 0.f;

  // ---- 2-deep pipeline: row load 1 iter ahead, csr 2 ahead; ONE scattered load/edge ----
  int k  = beg + slot;
  int kn = k + 8;
  int s_cur = (k  < end) ? csr[k]  : 0;
  int s_nxt = (kn < end) ? csr[kn] : 0;
  uint4 u_cur = *(const uint4*)(hb + (size_t)s_cur * 8 + hq * 4);
  while (k < end) {
    uint4 u_n = *(const uint4*)(hb + (size_t)s_nxt * 8 + hq * 4);  // next row
    int kf = kn + 8;
    int s_f = (kf < end) ? csr[kf] : 0;          // csr two ahead
    // unpack current row
    float h0 = bf_lo(u_cur.x), h1 = bf_hi(u_cur.x);
    float h2 = bf_lo(u_cur.y), h3 = bf_hi(u_cur.y);
    float h4 = bf_lo(u_cur.z), h5 = bf_hi(u_cur.z);
    float h6 = bf_lo(u_cur.w), h7 = bf_hi(u_cur.w);
    // als = dot(h, att_src) computed in registers (replaces the ab[] scattered load)
    float alsv = h0 * as_r[0] + h1 * as_r[1] + h2 * as_r[2] + h3 * as_r[3]
               + h4 * as_r[4] + h5 * as_r[5] + h6 * as_r[6] + h7 * as_r[7];
    float lg = alsv + aldv;
    lg = lg > 0.f ? lg : 0.2f * lg;              // leaky_relu slope 0.2
    float w = __expf(lg);
    z += w;
    acc[0] += w * h0; acc[1] += w * h1; acc[2] += w * h2; acc[3] += w * h3;
    acc[4] += w * h4; acc[5] += w * h5; acc[6] += w * h6; acc[7] += w * h7;
    k = kn; kn = kf; s_cur = s_nxt; s_nxt = s_f; u_cur = u_n;
  }

  #pragma unroll
  for (int off = 2; off < 16; off <<= 1) {      // combine slots, keep head bit
    z += __shfl_xor(z, off);
    #pragma unroll
    for (int c = 0; c < 8; ++c) acc[c] += __shfl_xor(acc[c], off);
  }
  float inv = 1.f / (z + 1e-16f);

  if (act && slot == 0) {                       // lanes sub=0(head0),1(head1)
    int ns = threadIdx.x >> 4;
    #pragma unroll
    for (int c = 0; c < 8; ++c) {
      float v = acc[c] * inv + sb[hq * 8 + c];
      v = v > 0.f ? v : expm1f(v);              // ELU
      sv[ns * 17 + hq * 8 + c] = v;
    }
  }
  __syncthreads();
  // ---- proj2 spread: thread j<64 = (node ns, out channel) : 16 MACs ----
  {
    int j = threadIdx.x;
    if (j < 64) {
      int ns = j >> 3, out = j & 7;
      int nid2 = blockIdx.x * 8 + ns;
      if (nid2 < n) {
        float h2v = 0.f;
        #pragma unroll
        for (int kk = 0; kk < 16; ++kk) h2v += sv[ns * 17 + kk] * W2s[kk * 8 + out];
        ((unsigned short*)hb2)[(size_t)nid2 * 8 + out] = f2bf1(h2v);
        sh2[ns * 9 + out] = h2v;
      }
    }
  }
  __syncthreads();
  // ---- ald2 dots: thread j<8 = node ----
  {
    int j = threadIdx.x;
    if (j < 8) {
      int nid2 = blockIdx.x * 8 + j;
      if (nid2 < n) {
        float d20 = 0.f, d21 = 0.f;
        #pragma unroll
        for (int c = 0; c < 4; ++c) {
          d20 += sh2[j * 9 + c] * ad2s[c];
          d21 += sh2[j * 9 + 4 + c] * ad2s[4 + c];
        }
        ((float2*)ald2)[nid2] = make_float2(d20, d21);
      }
    }
  }
}

// ---------------- Layer-2 gather: 1 scattered load/edge; als2 in-regs ------------
__global__ __launch_bounds__(TB) void
gat_gather2(const int* __restrict__ rowptr, const int* __restrict__ csr,
            const unsigned* __restrict__ hb2, const float* __restrict__ ald2,
            const void* __restrict__ bias, const void* __restrict__ as2g,
            void* __restrict__ outp, int n, const unsigned short* __restrict__ xb) {
  const int isf = detect_isf(xb);
  __shared__ float sb[8];
  __shared__ float as2s[8];
  if (threadIdx.x < 8) sb[threadIdx.x] = ldany(bias, threadIdx.x, isf);
  if (threadIdx.x >= 8 && threadIdx.x < 16) as2s[threadIdx.x - 8] = ldany(as2g, threadIdx.x - 8, isf);
  __syncthreads();

  const int t = blockIdx.x * TB + threadIdx.x;
  const int sub = t & 15, nid = t >> 4;
  const int slot = sub >> 1, hq = sub & 1;      // 8 edge slots x 2 head-lanes
  const bool act = nid < n;
  int beg = 0, end = 0;
  float aldv = 0.f;
  float as_r[4];
  #pragma unroll
  for (int c = 0; c < 4; ++c) as_r[c] = as2s[hq * 4 + c];
  if (act) {
    beg = rowptr[nid];
    end = rowptr[nid + 1];
    aldv = ald2[(size_t)nid * 2 + hq];
  }

  float a0 = 0.f, a1 = 0.f, a2 = 0.f, a3 = 0.f, z = 0.f;

  int k  = beg + slot;
  int kn = k + 8;
  int s_cur = (k  < end) ? csr[k]  : 0;
  int s_nxt = (kn < end) ? csr[kn] : 0;
  uint2 u_cur = *(const uint2*)(hb2 + (size_t)s_cur * 4 + hq * 2);
  while (k < end) {
    uint2 u_n = *(const uint2*)(hb2 + (size_t)s_nxt * 4 + hq * 2);
    int kf = kn + 8;
    int s_f = (kf < end) ? csr[kf] : 0;
    float h0 = bf_lo(u_cur.x), h1 = bf_hi(u_cur.x);
    float h2 = bf_lo(u_cur.y), h3 = bf_hi(u_cur.y);
    float alsv = h0 * as_r[0] + h1 * as_r[1] + h2 * as_r[2] + h3 * as_r[3];
    float lg = alsv + aldv;
    lg = lg > 0.f ? lg : 0.2f * lg;
    float w = __expf(lg);
    z += w;
    a0 += w * h0; a1 += w * h1; a2 += w * h2; a3 += w * h3;
    k = kn; kn = kf; s_cur = s_nxt; s_nxt = s_f; u_cur = u_n;
  }

  #pragma unroll
  for (int off = 2; off < 16; off <<= 1) {      // combine slots, keep head bit
    z  += __shfl_xor(z, off);
    a0 += __shfl_xor(a0, off); a1 += __shfl_xor(a1, off);
    a2 += __shfl_xor(a2, off); a3 += __shfl_xor(a3, off);
  }

  if (act && slot == 0) {                       // lanes sub=0(head0),1(head1)
    float inv = 1.f / (z + 1e-16f);
    float v0 = a0 * inv + sb[hq * 4 + 0];
    float v1 = a1 * inv + sb[hq * 4 + 1];
    float v2 = a2 * inv + sb[hq * 4 + 2];
    float v3 = a3 * inv + sb[hq * 4 + 3];
    if (isf) {
      ((float4*)outp)[(size_t)nid * 2 + hq] = make_float4(v0, v1, v2, v3);
    } else {
      ((uint2*)outp)[(size_t)nid * 2 + hq] = make_uint2(f2bf2(v0, v1), f2bf2(v2, v3));
    }
  }
}

extern "C" void kernel_launch(void* const* d_in, const int* in_sizes, int n_in,
                              void* d_out, int out_size, void* d_ws, size_t ws_size,
                              hipStream_t stream) {
  const unsigned short* xb = (const unsigned short*)d_in[0];
  const int*  ei  = (const int*)d_in[1];
  const void* W1  = d_in[2];
  const void* as1 = d_in[3];
  const void* ad1 = d_in[4];
  const void* b1  = d_in[5];
  const void* W2  = d_in[6];
  const void* as2 = d_in[7];
  const void* ad2 = d_in[8];
  const void* b2  = d_in[9];

  const int n  = in_sizes[0] / 16;        // 100000
  const int E  = in_sizes[1] / 2;         // 3200000
  const int Et = E + n;                   // + self-loops
  const int NB = (n + BSZ - 1) >> BSH;    // 391 buckets
  const int EB = (Et + CHUNK - 1) / CHUNK;  // 403 edge-chunk blocks (<= EBP)

  // ---- workspace layout ----
  char* base = (char*)d_ws;
  int* gcnt   = (int*)(base + 64);        // NB+1
  int* gbase_ = gcnt + (NB + 1);          // NB+1
  int* rowptr = gbase_ + (NB + 1);        // n+1
  int* bcnt   = rowptr + (n + 1);         // NB * EBP
  int* csr    = bcnt + (size_t)NB * EBP;  // Et
  int* packed = csr + Et;                 // Et
  size_t off1 = 64 + sizeof(int) * ((size_t)(NB + 1) * 2 + (size_t)(n + 1)
                                    + (size_t)NB * EBP + 2 * (size_t)Et);
  off1 = (off1 + 255) & ~(size_t)255;
  unsigned* hb1  = (unsigned*)(base + off1);                  // 32n B
  float*    ald1 = (float*)(base + off1 + (size_t)32 * n);    // 8n B
  size_t off2 = off1 + (size_t)40 * n;
  off2 = (off2 + 255) & ~(size_t)255;
  unsigned* hb2  = (unsigned*)(base + off2);                  // 16n B
  float*    ald2 = (float*)(base + off2 + (size_t)16 * n);    // 8n B

  const int pblk = (n + TBB - 1) / TBB;           // proj blocks
  const int gblk = (16 * n + TB - 1) / TB;        // 16 threads per node

  // ---- fused: edge histogram + layer-1 proj ----
  k_bcount_proj<<<EB + pblk, TBB, 0, stream>>>(ei, E, Et, NB, EB, bcnt,
                                               xb, W1, ad1, hb1, ald1, n);
  k_blockpfx<<<NB, EBP, 0, stream>>>(bcnt, gcnt, EB, NB);
  k_bscan<<<1, 1024, 0, stream>>>(gcnt, gbase_, NB, Et);
  k_bscatter<<<EB, TBB, 0, stream>>>(ei, E, Et, NB, gbase_, bcnt, packed);
  k_localsort<<<NB, TLS, 0, stream>>>(gbase_, packed, rowptr, csr, n, Et);

  // ---- Layer 1 gather + finalize + fused proj2 -> layer-2 tables ----
  gat_gather1<<<gblk, TB, 0, stream>>>(rowptr, csr, hb1, ald1, b1, as1,
                                       W2, ad2, hb2, ald2, n, xb);

  // ---- Layer 2 gather + finalize -> d_out ----
  gat_gather2<<<gblk, TB, 0, stream>>>(rowptr, csr, hb2, ald2, b2, as2,
                                       d_out, n, xb);
}